// Round 6
// baseline (500.432 us; speedup 1.0000x reference)
//
#include <hip/hip_runtime.h>

// TemporalAttention N=8192 D=1024, fp32 in/out, fp16-MFMA internals.
// v13 = v12 with the schedule DE-PINNED (the one diff vs the m201 template):
//   - removed all __builtin_amdgcn_sched_barrier(0)  [m141: pinning = 510 vs
//     874 TF; rule #18 applies only to inline-asm ds_reads, ours are
//     compiler-visible loads]
//   - per-phase s_waitcnt lgkmcnt(0) is now a bare asm (no "memory" clobber)
//     so the compiler may interleave next-phase ds_reads / addr math into
//     the MFMA cluster (all reads within a tile target stable slot regions).
//   - once-per-tile vmcnt wait KEEPS the memory clobber (pins reads-after-
//     publish across the ring boundary).
// Ring/stage/barrier plan byte-identical to v12 (5x harness-passed):
// Engine C (256x256, A 2-slot + B 3-slot = 160 KiB, 4 phases, vmcnt(6) once
// per K-tile) for stats + QK-proj; engine B (256x128, 3-slot, PH=2,
// vmcnt(6)) for PV + V-proj. XOR chunk swizzle (chunk c at c^(row&7), via
// pre-swizzled global source, linear gload_lds dest): 0 bank conflicts.

using half8   = __attribute__((ext_vector_type(8))) _Float16;
using half4   = __attribute__((ext_vector_type(4))) _Float16;
using floatx4 = __attribute__((ext_vector_type(4))) float;

__device__ __forceinline__ void gload_lds16(const void* g, void* l) {
  __builtin_amdgcn_global_load_lds((const __attribute__((address_space(1))) void*)g,
                                   (__attribute__((address_space(3))) void*)l,
                                   16, 0, 0);
}

template<int N> __device__ __forceinline__ void waitv() {
  if constexpr (N == 6) asm volatile("s_waitcnt vmcnt(6)" ::: "memory");
  else                  asm volatile("s_waitcnt vmcnt(0)" ::: "memory");
}
__device__ __forceinline__ void waitl0() {
  asm volatile("s_waitcnt lgkmcnt(0)");   // bare: not a compiler fence
}

// ---------------- engine C: 256x256, A 2-slot + B 3-slot, 4 phases ----------
// 8 waves 2Mx4N; per-wave 128x64 (MI=8, NJ=4). K tiles of 64 (NT >= 4).
template<int MI, int NJ>
__device__ __forceinline__ void kloop_c(
    const _Float16* __restrict__ A, const _Float16* __restrict__ B,
    long rowBase, long colBase, int lda, int ldb, int K,
    _Float16* __restrict__ As, _Float16* __restrict__ Bs,
    floatx4 (&acc)[MI][NJ])
{
  static_assert(MI == 8 && NJ == 4);
  const int tid = threadIdx.x;
  const int w = tid >> 6, lane = tid & 63;
  const int q = lane >> 4, l15 = lane & 15;
  const int wr = w >> 2, wcn = w & 3;

  // staging: pass p covers rows [p*64, p*64+64); source chunk pre-swizzled
  // (chunk c stored at c^(row&7)); LDS dest linear.
  const int sc = ((lane & 7) ^ (lane >> 3)) << 3;
  const _Float16* Agp[4]; const _Float16* Bgp[4];
#pragma unroll
  for (int p = 0; p < 4; ++p) {
    Agp[p] = A + (rowBase + p * 64 + (tid >> 3)) * (long)lda + sc;
    Bgp[p] = B + (colBase + p * 64 + (tid >> 3)) * (long)ldb + sc;
  }
  const int ldsOff = tid * 8;

  const int aRow = wr * 128 + l15;
  const int bRow = wcn * 64 + l15;
  const int cx = l15 & 7;
  const int pc0 = (q ^ cx) << 3, pc1 = ((4 + q) ^ cx) << 3;

  auto stageA = [&](int t, int h) {          // half h of tile t -> slot t&1
    _Float16* dst = As + (t & 1) * (256 * 64);
    const int ko = t << 6;
#pragma unroll
    for (int p = 2 * h; p < 2 * h + 2; ++p)
      gload_lds16(Agp[p] + ko, dst + p * 4096 + ldsOff);
  };
  auto stageB = [&](int t, int h, int slot) {
    _Float16* dst = Bs + slot * (256 * 64);
    const int ko = t << 6;
#pragma unroll
    for (int p = 2 * h; p < 2 * h + 2; ++p)
      gload_lds16(Bgp[p] + ko, dst + p * 4096 + ldsOff);
  };

  const int NT = K >> 6;                      // >= 4 for all uses here
  // prologue (oldest-first so vmcnt(6) retires tile 0): tile0 x4, tile1 x3.
  stageB(0, 0, 0); stageB(0, 1, 0); stageA(0, 0); stageA(0, 1);
  stageB(1, 0, 1); stageB(1, 1, 1); stageA(1, 0);
  waitv<6>(); __builtin_amdgcn_s_barrier();

  int bs_ = 0;                                // B slot of tile t = t%3
  for (int t = 0; t < NT; ++t) {
    const _Float16* Asl = As + (t & 1) * (256 * 64);
    const _Float16* Bsl = Bs + bs_ * (256 * 64);
    const int bs2 = (bs_ == 0) ? 2 : bs_ - 1; // (t+2)%3
    half8 b0[NJ], b1[NJ], a0lo[MI / 2], a0hi[MI / 2], a1[MI];

    // ---- ph1: read b[kk0]+a[kk0]lo | stage A-h1(t+1) | MFMA kk0 rows-lo
#pragma unroll
    for (int j = 0; j < NJ; ++j)
      b0[j] = *(const half8*)&Bsl[(bRow + 16 * j) * 64 + pc0];
#pragma unroll
    for (int i = 0; i < MI / 2; ++i)
      a0lo[i] = *(const half8*)&Asl[(aRow + 16 * i) * 64 + pc0];
    if (t + 1 < NT) stageA(t + 1, 1);
    __builtin_amdgcn_s_barrier();
    waitl0();
    __builtin_amdgcn_s_setprio(1);
#pragma unroll
    for (int i = 0; i < MI / 2; ++i)
#pragma unroll
      for (int j = 0; j < NJ; ++j)
        acc[i][j] = __builtin_amdgcn_mfma_f32_16x16x32_f16(a0lo[i], b0[j], acc[i][j], 0, 0, 0);
    __builtin_amdgcn_s_setprio(0);
    __builtin_amdgcn_s_barrier();

    // ---- ph2: read a[kk0]hi + b[kk1] | stage B-h0(t+2) | MFMA kk0 rows-hi
#pragma unroll
    for (int i = 0; i < MI / 2; ++i)
      a0hi[i] = *(const half8*)&Asl[(aRow + 16 * (MI / 2 + i)) * 64 + pc0];
#pragma unroll
    for (int j = 0; j < NJ; ++j)
      b1[j] = *(const half8*)&Bsl[(bRow + 16 * j) * 64 + pc1];
    if (t + 2 < NT) stageB(t + 2, 0, bs2);
    __builtin_amdgcn_s_barrier();
    waitl0();
    __builtin_amdgcn_s_setprio(1);
#pragma unroll
    for (int i = 0; i < MI / 2; ++i)
#pragma unroll
      for (int j = 0; j < NJ; ++j)
        acc[MI / 2 + i][j] = __builtin_amdgcn_mfma_f32_16x16x32_f16(a0hi[i], b0[j], acc[MI / 2 + i][j], 0, 0, 0);
    __builtin_amdgcn_s_setprio(0);
    __builtin_amdgcn_s_barrier();

    // ---- ph3: read a[kk1] (all) | stage B-h1(t+2) | MFMA kk1 rows-lo
#pragma unroll
    for (int i = 0; i < MI; ++i)
      a1[i] = *(const half8*)&Asl[(aRow + 16 * i) * 64 + pc1];
    if (t + 2 < NT) stageB(t + 2, 1, bs2);
    __builtin_amdgcn_s_barrier();
    waitl0();
    __builtin_amdgcn_s_setprio(1);
#pragma unroll
    for (int i = 0; i < MI / 2; ++i)
#pragma unroll
      for (int j = 0; j < NJ; ++j)
        acc[i][j] = __builtin_amdgcn_mfma_f32_16x16x32_f16(a1[i], b1[j], acc[i][j], 0, 0, 0);
    __builtin_amdgcn_s_setprio(0);
    __builtin_amdgcn_s_barrier();

    // ---- ph4: stage A-h0(t+2) | MFMA kk1 rows-hi | counted wait + barrier
    if (t + 2 < NT) stageA(t + 2, 0);         // A slot t&1: reads done ph3
    __builtin_amdgcn_s_barrier();
    __builtin_amdgcn_s_setprio(1);
#pragma unroll
    for (int i = 0; i < MI / 2; ++i)
#pragma unroll
      for (int j = 0; j < NJ; ++j)
        acc[MI / 2 + i][j] = __builtin_amdgcn_mfma_f32_16x16x32_f16(a1[MI / 2 + i], b1[j], acc[MI / 2 + i][j], 0, 0, 0);
    __builtin_amdgcn_s_setprio(0);
    if (t < NT - 2)       { waitv<6>(); __builtin_amdgcn_s_barrier(); }
    else if (t == NT - 2) { waitv<0>(); __builtin_amdgcn_s_barrier(); }
    bs_ = (bs_ == 2) ? 0 : bs_ + 1;
  }
}

// ---------------- engine B (v10-proven): 3-slot ring, PH=2 ------------------
template<int BM, int BN, int WM, int WN, int SLOTS, int PH, int MI, int NJ>
__device__ __forceinline__ void kloop_f(
    const _Float16* __restrict__ A, const _Float16* __restrict__ B,
    long rowBase, long colBase, int lda, int ldb, int K,
    _Float16* __restrict__ As, _Float16* __restrict__ Bs,
    floatx4 (&acc)[MI][NJ])
{
  static_assert(MI == BM / WM / 16 && NJ == BN / WN / 16 && MI % PH == 0);
  constexpr int LA = BM / 64, LB = BN / 64;
  constexpr int RP = MI / PH;
  const int tid = threadIdx.x;
  const int w = tid >> 6, lane = tid & 63;
  const int q = lane >> 4, l15 = lane & 15;
  const int wr = w / WN, wcn = w & (WN - 1);

  const int sc = ((lane & 7) ^ (lane >> 3)) << 3;
  const _Float16* Agp[LA]; const _Float16* Bgp[LB];
#pragma unroll
  for (int p = 0; p < LA; ++p)
    Agp[p] = A + (rowBase + p * 64 + (tid >> 3)) * (long)lda + sc;
#pragma unroll
  for (int p = 0; p < LB; ++p)
    Bgp[p] = B + (colBase + p * 64 + (tid >> 3)) * (long)ldb + sc;
  const int ldsOff = tid * 8;

  const int aRow = wr * (BM / WM) + l15;
  const int bRow = wcn * (BN / WN) + l15;
  const int cx = l15 & 7;

  auto issueA = [&](int t, int s) {
    _Float16* Asl = As + s * (BM * 64);
    const int ko = t << 6;
#pragma unroll
    for (int p = 0; p < LA; ++p) gload_lds16(Agp[p] + ko, Asl + p * 4096 + ldsOff);
  };
  auto issueB = [&](int t, int s) {
    _Float16* Bsl = Bs + s * (BN * 64);
    const int ko = t << 6;
#pragma unroll
    for (int p = 0; p < LB; ++p) gload_lds16(Bgp[p] + ko, Bsl + p * 4096 + ldsOff);
  };

  half8 bfr[2][NJ];

  auto tile = [&](int t, int slot, bool doStage, int ew) {
    const _Float16* Asl = As + slot * (BM * 64);
    const _Float16* Bsl = Bs + slot * (BN * 64);
    const int st = t + SLOTS - 1;
    const int ss = (SLOTS == 2) ? (slot ^ 1) : (st % 3);
#pragma unroll
    for (int ph = 0; ph < PH; ++ph) {
      half8 afr[2][RP];
      if (ph == 0) {
#pragma unroll
        for (int kk = 0; kk < 2; ++kk) {
          const int pc = ((kk * 4 + q) ^ cx) << 3;
#pragma unroll
          for (int j = 0; j < NJ; ++j)
            bfr[kk][j] = *(const half8*)&Bsl[(bRow + 16 * j) * 64 + pc];
        }
      }
#pragma unroll
      for (int kk = 0; kk < 2; ++kk) {
        const int pc = ((kk * 4 + q) ^ cx) << 3;
#pragma unroll
        for (int r = 0; r < RP; ++r)
          afr[kk][r] = *(const half8*)&Asl[(aRow + 16 * (ph * RP + r)) * 64 + pc];
      }
      if (doStage && ph == 0) issueA(st, ss);
      if (doStage && ph == 1) issueB(st, ss);
      __builtin_amdgcn_s_barrier();
      waitl0();
      __builtin_amdgcn_s_setprio(1);
#pragma unroll
      for (int kk = 0; kk < 2; ++kk)
#pragma unroll
        for (int r = 0; r < RP; ++r)
#pragma unroll
          for (int j = 0; j < NJ; ++j)
            acc[ph * RP + r][j] = __builtin_amdgcn_mfma_f32_16x16x32_f16(
                afr[kk][r], bfr[kk][j], acc[ph * RP + r][j], 0, 0, 0);
      __builtin_amdgcn_s_setprio(0);
      if (ph == PH - 1) {
        if (ew == 6)      waitv<6>();
        else if (ew == 0) waitv<0>();
        if (ew >= 0) __builtin_amdgcn_s_barrier();
      } else {
        __builtin_amdgcn_s_barrier();
      }
    }
  };

  const int NT = K >> 6;
  static_assert(SLOTS == 3);
  issueA(0, 0); issueB(0, 0);
  issueA(1, 1); issueB(1, 1);
  waitv<6>(); __builtin_amdgcn_s_barrier();
  int cs = 0;
  for (int t = 0; t < NT - 1; ++t) {
    const bool st = (t + 2 < NT);
    tile(t, cs, st, (t < NT - 2) ? 6 : 0);
    cs = (cs == 2) ? 0 : cs + 1;
  }
  tile(NT - 1, cs, false, -1);
}

// ---------------- kernels ---------------------------------------------------
// BIAS_MODE: 0 none, 1 add per-col, 2 add per-row, 3 MUL per-row (invL).
// OUT_MODE: 0 fp16, 2 fp32.  SWZ: XCD grouping via ty = bflat % gridDim.y.
template<int BM, int BN, int WM, int WN, int SLOTS, int PH,
         int BIAS_MODE, int OUT_MODE, int SWZ>
__global__ __launch_bounds__(512, 2)
void gemm256_k(const _Float16* __restrict__ A, const _Float16* __restrict__ B,
               void* __restrict__ Cout, const float* __restrict__ bias,
               int lda, int ldb, int ldc, int K, float outScale)
{
  constexpr int MI = BM / WM / 16, NJ = BN / WN / 16;
  __shared__ __align__(16) _Float16 As[SLOTS * BM * 64];
  __shared__ __align__(16) _Float16 Bs[SLOTS * BN * 64];

  int tx, ty;
  if (SWZ) {
    const int bflat = blockIdx.y * gridDim.x + blockIdx.x;
    ty = bflat % gridDim.y;
    tx = bflat / gridDim.y;
  } else {
    tx = blockIdx.x; ty = blockIdx.y;
  }
  const long rowBase = (long)ty * BM;
  const long colBase = (long)tx * BN;

  floatx4 acc[MI][NJ] = {};
  kloop_f<BM, BN, WM, WN, SLOTS, PH, MI, NJ>(A, B, rowBase, colBase, lda, ldb, K,
                                             As, Bs, acc);

  const int tid = threadIdx.x;
  const int w = tid >> 6, lane = tid & 63;
  const int q = lane >> 4, l15 = lane & 15;
  const int wr = w / WN, wcn = w & (WN - 1);
#pragma unroll
  for (int i = 0; i < MI; ++i) {
#pragma unroll
    for (int r = 0; r < 4; ++r) {
      const long rowg = rowBase + wr * (BM / WM) + 16 * i + q * 4 + r;
#pragma unroll
      for (int j = 0; j < NJ; ++j) {
        const long colg = colBase + wcn * (BN / WN) + 16 * j + l15;
        float v = acc[i][j][r];
        if (BIAS_MODE == 1) v += bias[colg];
        if (BIAS_MODE == 2) v += bias[rowg];
        if (BIAS_MODE == 3) v *= bias[rowg];
        v *= outScale;
        if (OUT_MODE == 2) ((float*)Cout)[rowg * ldc + colg] = v;
        else               ((_Float16*)Cout)[rowg * ldc + colg] = (_Float16)v;
      }
    }
  }
}

// Engine-C GEMM (256x256): used for QK-proj.
template<int BIAS_MODE, int OUT_MODE>
__global__ __launch_bounds__(512, 2)
void gemm256c_k(const _Float16* __restrict__ A, const _Float16* __restrict__ B,
                void* __restrict__ Cout, const float* __restrict__ bias,
                int lda, int ldb, int ldc, int K, float outScale)
{
  __shared__ __align__(16) _Float16 As[2 * 256 * 64];
  __shared__ __align__(16) _Float16 Bs[3 * 256 * 64];
  const long rowBase = (long)blockIdx.y * 256;
  const long colBase = (long)blockIdx.x * 256;

  floatx4 acc[8][4] = {};
  kloop_c<8, 4>(A, B, rowBase, colBase, lda, ldb, K, As, Bs, acc);

  const int tid = threadIdx.x;
  const int w = tid >> 6, lane = tid & 63;
  const int q = lane >> 4, l15 = lane & 15;
  const int wr = w >> 2, wcn = w & 3;
#pragma unroll
  for (int i = 0; i < 8; ++i) {
#pragma unroll
    for (int r = 0; r < 4; ++r) {
      const long rowg = rowBase + wr * 128 + 16 * i + q * 4 + r;
#pragma unroll
      for (int j = 0; j < 4; ++j) {
        const long colg = colBase + wcn * 64 + 16 * j + l15;
        float v = acc[i][j][r];
        if (BIAS_MODE == 1) v += bias[colg];
        if (BIAS_MODE == 2) v += bias[rowg];
        v *= outScale;
        if (OUT_MODE == 2) ((float*)Cout)[rowg * ldc + colg] = v;
        else               ((_Float16*)Cout)[rowg * ldc + colg] = (_Float16)v;
      }
    }
  }
}

// U = exp(qkScale*(Q*K^T) + decay_bias - 4), fp16; per-(row,col-tile) sums.
// Engine C; ts read from global in epilogue; sL scratch aliased into As.
__global__ __launch_bounds__(512, 2)
void gemm_statsC_k(const _Float16* __restrict__ A, const _Float16* __restrict__ B,
                   const float* __restrict__ ts, _Float16* __restrict__ U,
                   float* __restrict__ part, int lda, int ldb, int N, int K,
                   float qkScale)
{
  __shared__ __align__(16) _Float16 As[2 * 256 * 64];
  __shared__ __align__(16) _Float16 Bs[3 * 256 * 64];
  const int tid = threadIdx.x;
  const long rowBase = (long)blockIdx.y * 256;
  const long colBase = (long)blockIdx.x * 256;

  floatx4 acc[8][4] = {};
  kloop_c<8, 4>(A, B, rowBase, colBase, lda, ldb, K, As, Bs, acc);

  const int w = tid >> 6, lane = tid & 63;
  const int q = lane >> 4, l15 = lane & 15;
  const int wr = w >> 2, wcn = w & 3;
  const float inv_td = 1.0f / 86400.0f;

  float tc[4];
#pragma unroll
  for (int j = 0; j < 4; ++j) tc[j] = ts[colBase + wcn * 64 + 16 * j + l15];

  float* sl = (float*)As;             // k-loop LDS reads all done (ph3 barrier)
  __syncthreads();
  // u = exp(s - 4); s = qk/32 + log-decay ~ qk/32 - |dt|/TD (exact to 2.2e-6).
#pragma unroll
  for (int i = 0; i < 8; ++i) {
#pragma unroll
    for (int r = 0; r < 4; ++r) {
      const int rowl = wr * 128 + 16 * i + q * 4 + r;
      const float tr = ts[rowBase + rowl];
      float ls = 0.0f;
#pragma unroll
      for (int j = 0; j < 4; ++j) {
        const int coll = wcn * 64 + 16 * j + l15;
        const float sv = acc[i][j][r] * qkScale
                       - fabsf(tr - tc[j]) * inv_td - 4.0f;
        const float u = __expf(sv);
        ls += u;
        U[(rowBase + rowl) * (long)N + (colBase + coll)] = (_Float16)u;
      }
      for (int mask = 1; mask <= 8; mask <<= 1)
        ls += __shfl_xor(ls, mask, 64);
      if (l15 == 0) sl[(wr * 4 + wcn) * 128 + 16 * i + 4 * q + r] = ls;
    }
  }
  __syncthreads();
  if (tid < 256) {
    const int band = tid & 127, hi = tid >> 7;
    part[(rowBase + tid) * 32 + blockIdx.x] =
        sl[(hi * 4 + 0) * 128 + band] + sl[(hi * 4 + 1) * 128 + band] +
        sl[(hi * 4 + 2) * 128 + band] + sl[(hi * 4 + 3) * 128 + band];
  }
}

__global__ void combine_k(const float* __restrict__ part, float* __restrict__ invL) {
  const int r = blockIdx.x * 256 + threadIdx.x;
  float L = 0.0f;
  for (int c = 0; c < 32; ++c) L += part[(long)r * 32 + c];
  invL[r] = 1.0f / L;
}

// fp32 -> fp16, 4/thread
__global__ void cvt_k(const float* __restrict__ in, _Float16* __restrict__ out, int n) {
  const int i = (blockIdx.x * 256 + threadIdx.x) * 4;
  if (i >= n) return;
  const float4 v = *(const float4*)(in + i);
  half4 o = { (_Float16)v.x, (_Float16)v.y, (_Float16)v.z, (_Float16)v.w };
  *(half4*)(out + i) = o;
}

extern "C" void kernel_launch(void* const* d_in, const int* in_sizes, int n_in,
                              void* d_out, int out_size, void* d_ws, size_t ws_size,
                              hipStream_t stream)
{
  (void)in_sizes; (void)n_in; (void)out_size; (void)ws_size;
  const int N = 8192, D = 1024;
  const float* x  = (const float*)d_in[0];
  const float* ts = (const float*)d_in[1];
  const float* Wq = (const float*)d_in[2];
  const float* bq = (const float*)d_in[3];
  const float* Wk = (const float*)d_in[4];
  const float* bk = (const float*)d_in[5];
  const float* Wv = (const float*)d_in[6];
  const float* bv = (const float*)d_in[7];

  char* p = (char*)d_ws;
  auto grab = [&](size_t bytes) {
    char* r = p;
    p += (bytes + 255) & ~(size_t)255;
    return r;
  };
  _Float16* xh    = (_Float16*)grab((size_t)N * D * 2);
  _Float16* wqkh  = (_Float16*)grab((size_t)2 * D * D * 2); // Wq rows then Wk rows
  _Float16* wvh   = (_Float16*)grab((size_t)D * D * 2);
  _Float16* QKcat = (_Float16*)grab((size_t)N * 2 * D * 2); // [N x 2D], Q | K
  _Float16* VTh   = (_Float16*)grab((size_t)D * N * 2);     // V^T [D x N]
  _Float16* Uh    = (_Float16*)grab((size_t)N * N * 2);     // U = exp(S - 4)
  float*    part  = (float*)grab((size_t)N * 32 * sizeof(float));
  float*    invL  = (float*)grab((size_t)N * sizeof(float));
  float*    bcat  = (float*)grab((size_t)2 * D * sizeof(float));

  cvt_k<<<N * D / 1024, 256, 0, stream>>>(x,  xh,  N * D);
  cvt_k<<<D * D / 1024, 256, 0, stream>>>(Wq, wqkh,         D * D);
  cvt_k<<<D * D / 1024, 256, 0, stream>>>(Wk, wqkh + D * D, D * D);
  cvt_k<<<D * D / 1024, 256, 0, stream>>>(Wv, wvh, D * D);
  hipMemcpyAsync(bcat,     bq, D * sizeof(float), hipMemcpyDeviceToDevice, stream);
  hipMemcpyAsync(bcat + D, bk, D * sizeof(float), hipMemcpyDeviceToDevice, stream);

  dim3 blk(512);
  // [Q | K] = x [Wq;Wk]^T + [bq|bk]; engine C -> grid (8,32)=256 wg.
  gemm256c_k<1, 0><<<dim3(2 * D / 256, N / 256), blk, 0, stream>>>(
      xh, wqkh, QKcat, bcat, D, D, 2 * D, D, 1.0f);
  // V^T = Wv x^T + bv; engine B -> grid (64,4)=256 wg.
  gemm256_k<256, 128, 4, 2, 3, 2, 2, 0, 0><<<dim3(N / 128, D / 256), blk, 0, stream>>>(
      wvh, xh, VTh, bv, D, D, N, D, 1.0f);
  // U = exp(QK^T/32 + decay - 4) + partial row sums; engine C, (32,32)=1024 wg.
  gemm_statsC_k<<<dim3(N / 256, N / 256), blk, 0, stream>>>(
      QKcat, QKcat + D, ts, Uh, part, 2 * D, 2 * D, N, D, 1.0f / 32.0f);
  combine_k<<<N / 256, 256, 0, stream>>>(part, invL);
  // O = (U V) * invL; engine B 3-slot -> grid (8,32)=256 wg, XCD swz.
  gemm256_k<256, 128, 4, 2, 3, 2, 3, 2, 1><<<dim3(D / 128, N / 256), blk, 0, stream>>>(
      Uh, VTh, d_out, invL, N, N, D, N, 1.0f);
}

// Round 7
// 464.327 us; speedup vs baseline: 1.0778x; 1.0778x over previous
//
#include <hip/hip_runtime.h>

// TemporalAttention N=8192 D=1024, fp32 in/out, fp16-MFMA internals.
// v14: cross-phase software pipeline. Cycle audit of v7-v13 (all ~184us):
// MFMA 2483cy + LDS-reads ~2300cy + stage 512cy + residue = 6908cy/K-tile
// = measured -> reads and MFMA were SERIALIZED in every variant. v14 puts
// reads one phase AHEAD of MFMA in named registers with NO fences between
// (no inner barriers, no per-phase lgkm asm, no setprio): compiler emits
// fine-grained lgkmcnt and reads drain under the MFMA stream.
// Engine S (256x256, QK-proj + stats): A2+B2 slots (128KB), 2 barriers/tile:
//   M = [lgkmcnt(0) + s_barrier] after tile's last read, before staging t+2
//   into the just-retired slot (t+2)&1 == t&1; boundary = [vmcnt(8) counted
//   + s_barrier] publishing t+1 (t+2's 8 loads stay in flight ~1 region).
// Engine V (256x128, PV + V-proj): A3+B3 slots (144KB), no mid-barrier
//   (stage slot (t+2)%3 disjoint from live slots), vmcnt(6) counted.
// All LDS reads retire before any overwrite: every read is consumed by an
// MFMA before region end (FIFO lgkm => compiler's per-use waits drain all).
// XOR chunk swizzle (chunk c at c^(row&7), pre-swizzled global source,
// linear gload_lds dest): unchanged, 0 bank conflicts since v7.

using half8   = __attribute__((ext_vector_type(8))) _Float16;
using half4   = __attribute__((ext_vector_type(4))) _Float16;
using floatx4 = __attribute__((ext_vector_type(4))) float;

__device__ __forceinline__ void gload_lds16(const void* g, void* l) {
  __builtin_amdgcn_global_load_lds((const __attribute__((address_space(1))) void*)g,
                                   (__attribute__((address_space(3))) void*)l,
                                   16, 0, 0);
}

template<int N> __device__ __forceinline__ void waitv() {
  if constexpr (N == 8)      asm volatile("s_waitcnt vmcnt(8)" ::: "memory");
  else if constexpr (N == 6) asm volatile("s_waitcnt vmcnt(6)" ::: "memory");
  else                       asm volatile("s_waitcnt vmcnt(0)" ::: "memory");
}

#define MFMA16(ar, br, accrow)                                              \
  _Pragma("unroll")                                                         \
  for (int i_ = 0; i_ < 4; ++i_)                                            \
    _Pragma("unroll")                                                       \
    for (int j_ = 0; j_ < 4; ++j_)                                          \
      accrow[i_][j_] = __builtin_amdgcn_mfma_f32_16x16x32_f16(              \
          ar[i_], br[j_], accrow[i_][j_], 0, 0, 0);

// ---------------- engine S: 256x256, A2+B2, pipelined, 2 barriers/tile ------
// 8 waves 2Mx4N; per-wave 128x64 (acc[8][4]).
__device__ __forceinline__ void kloop_s(
    const _Float16* __restrict__ A, const _Float16* __restrict__ B,
    long rowBase, long colBase, int lda, int ldb, int K,
    _Float16* __restrict__ As, _Float16* __restrict__ Bs,
    floatx4 (&acc)[8][4])
{
  const int tid = threadIdx.x;
  const int w = tid >> 6, lane = tid & 63;
  const int q = lane >> 4, l15 = lane & 15;
  const int wr = w >> 2, wcn = w & 3;

  const int sc = ((lane & 7) ^ (lane >> 3)) << 3;
  const _Float16* Agp[4]; const _Float16* Bgp[4];
#pragma unroll
  for (int p = 0; p < 4; ++p) {
    Agp[p] = A + (rowBase + p * 64 + (tid >> 3)) * (long)lda + sc;
    Bgp[p] = B + (colBase + p * 64 + (tid >> 3)) * (long)ldb + sc;
  }
  const int ldsOff = tid * 8;

  const int aRow = wr * 128 + l15;
  const int bRow = wcn * 64 + l15;
  const int cx = l15 & 7;
  const int pc0 = (q ^ cx) << 3, pc1 = ((4 + q) ^ cx) << 3;

  auto stageA = [&](int t) {
    _Float16* dst = As + (t & 1) * 16384;
    const int ko = t << 6;
#pragma unroll
    for (int p = 0; p < 4; ++p) gload_lds16(Agp[p] + ko, dst + p * 4096 + ldsOff);
  };
  auto stageB = [&](int t) {
    _Float16* dst = Bs + (t & 1) * 16384;
    const int ko = t << 6;
#pragma unroll
    for (int p = 0; p < 4; ++p) gload_lds16(Bgp[p] + ko, dst + p * 4096 + ldsOff);
  };

  const int NT = K >> 6;
  stageA(0); stageB(0); stageA(1); stageB(1);
  waitv<8>(); __builtin_amdgcn_s_barrier();   // tile 0 published; t1 in flight

  for (int t = 0; t < NT; ++t) {
    const _Float16* Asl = As + (t & 1) * 16384;
    const _Float16* Bsl = Bs + (t & 1) * 16384;
    half8 b0[4], b1[4], a0lo[4], a0hi[4], a1lo[4], a1hi[4];

    // reads lead MFMA by one group; no fences between -> overlap.
#pragma unroll
    for (int j = 0; j < 4; ++j) b0[j]   = *(const half8*)&Bsl[(bRow + 16 * j) * 64 + pc0];
#pragma unroll
    for (int i = 0; i < 4; ++i) a0lo[i] = *(const half8*)&Asl[(aRow + 16 * i) * 64 + pc0];
#pragma unroll
    for (int i = 0; i < 4; ++i) a0hi[i] = *(const half8*)&Asl[(aRow + 16 * (4 + i)) * 64 + pc0];
    {
      floatx4 (&alo)[4][4] = *(floatx4(*)[4][4])&acc[0];
      MFMA16(a0lo, b0, alo);
    }
#pragma unroll
    for (int j = 0; j < 4; ++j) b1[j]   = *(const half8*)&Bsl[(bRow + 16 * j) * 64 + pc1];
#pragma unroll
    for (int i = 0; i < 4; ++i) a1lo[i] = *(const half8*)&Asl[(aRow + 16 * i) * 64 + pc1];
    {
      floatx4 (&ahi)[4][4] = *(floatx4(*)[4][4])&acc[4];
      MFMA16(a0hi, b0, ahi);
    }
#pragma unroll
    for (int i = 0; i < 4; ++i) a1hi[i] = *(const half8*)&Asl[(aRow + 16 * (4 + i)) * 64 + pc1];
    {
      floatx4 (&alo)[4][4] = *(floatx4(*)[4][4])&acc[0];
      MFMA16(a1lo, b1, alo);
    }

    // M: all LDS reads of tile t retired CU-wide; slot (t&1) now free.
    asm volatile("s_waitcnt lgkmcnt(0)" ::: "memory");
    __builtin_amdgcn_s_barrier();
    if (t + 2 < NT) { stageA(t + 2); stageB(t + 2); }
    {
      floatx4 (&ahi)[4][4] = *(floatx4(*)[4][4])&acc[4];
      MFMA16(a1hi, b1, ahi);
    }
    if (t < NT - 1) {
      if (t + 2 < NT) waitv<8>(); else waitv<0>();  // publish t+1; t+2 in flight
      __builtin_amdgcn_s_barrier();
    }
  }
}

// ---------------- engine V: 256x128, A3+B3, pipelined, 1 barrier/tile -------
// 8 waves 4Mx2N; per-wave 64x64 (acc[4][4]).
__device__ __forceinline__ void kloop_v(
    const _Float16* __restrict__ A, const _Float16* __restrict__ B,
    long rowBase, long colBase, int lda, int ldb, int K,
    _Float16* __restrict__ As, _Float16* __restrict__ Bs,
    floatx4 (&acc)[4][4])
{
  const int tid = threadIdx.x;
  const int w = tid >> 6, lane = tid & 63;
  const int q = lane >> 4, l15 = lane & 15;
  const int wr = w >> 1, wcn = w & 1;

  const int sc = ((lane & 7) ^ (lane >> 3)) << 3;
  const _Float16* Agp[4]; const _Float16* Bgp[2];
#pragma unroll
  for (int p = 0; p < 4; ++p)
    Agp[p] = A + (rowBase + p * 64 + (tid >> 3)) * (long)lda + sc;
#pragma unroll
  for (int p = 0; p < 2; ++p)
    Bgp[p] = B + (colBase + p * 64 + (tid >> 3)) * (long)ldb + sc;
  const int ldsOff = tid * 8;

  const int aRow = wr * 64 + l15;
  const int bRow = wcn * 64 + l15;
  const int cx = l15 & 7;
  const int pc0 = (q ^ cx) << 3, pc1 = ((4 + q) ^ cx) << 3;

  auto stage = [&](int t) {                    // 6 gloads; slot (t%3)
    const int s = t % 3;
    _Float16* dA = As + s * 16384;
    _Float16* dB = Bs + s * 8192;
    const int ko = t << 6;
#pragma unroll
    for (int p = 0; p < 4; ++p) gload_lds16(Agp[p] + ko, dA + p * 4096 + ldsOff);
#pragma unroll
    for (int p = 0; p < 2; ++p) gload_lds16(Bgp[p] + ko, dB + p * 4096 + ldsOff);
  };

  const int NT = K >> 6;
  stage(0); stage(1);
  waitv<6>(); __builtin_amdgcn_s_barrier();    // tile 0 published; t1 in flight

  for (int t = 0; t < NT; ++t) {
    const int s = t % 3;
    const _Float16* Asl = As + s * 16384;
    const _Float16* Bsl = Bs + s * 8192;
    half8 b0[4], b1[4], a0[4], a1[4];
#pragma unroll
    for (int j = 0; j < 4; ++j) b0[j] = *(const half8*)&Bsl[(bRow + 16 * j) * 64 + pc0];
#pragma unroll
    for (int i = 0; i < 4; ++i) a0[i] = *(const half8*)&Asl[(aRow + 16 * i) * 64 + pc0];
#pragma unroll
    for (int j = 0; j < 4; ++j) b1[j] = *(const half8*)&Bsl[(bRow + 16 * j) * 64 + pc1];
#pragma unroll
    for (int i = 0; i < 4; ++i) a1[i] = *(const half8*)&Asl[(aRow + 16 * i) * 64 + pc1];
    MFMA16(a0, b0, acc);
    if (t + 2 < NT) stage(t + 2);              // slot (t+2)%3: retired at t-1
    MFMA16(a1, b1, acc);
    if (t < NT - 1) {
      if (t + 2 < NT) waitv<6>(); else waitv<0>();
      __builtin_amdgcn_s_barrier();            // publish t+1
    }
  }
}

// ---------------- kernels ---------------------------------------------------
// BIAS_MODE: 0 none, 1 add per-col, 2 add per-row, 3 MUL per-row (invL).
// OUT_MODE: 0 fp16, 2 fp32.
template<int BIAS_MODE, int OUT_MODE>
__global__ __launch_bounds__(512, 2)
void gemmS_k(const _Float16* __restrict__ A, const _Float16* __restrict__ B,
             void* __restrict__ Cout, const float* __restrict__ bias,
             int lda, int ldb, int ldc, int K, float outScale)
{
  __shared__ __align__(16) _Float16 As[2 * 16384];
  __shared__ __align__(16) _Float16 Bs[2 * 16384];
  const long rowBase = (long)blockIdx.y * 256;
  const long colBase = (long)blockIdx.x * 256;

  floatx4 acc[8][4] = {};
  kloop_s(A, B, rowBase, colBase, lda, ldb, K, As, Bs, acc);

  const int tid = threadIdx.x;
  const int w = tid >> 6, lane = tid & 63;
  const int q = lane >> 4, l15 = lane & 15;
  const int wr = w >> 2, wcn = w & 3;
#pragma unroll
  for (int i = 0; i < 8; ++i) {
#pragma unroll
    for (int r = 0; r < 4; ++r) {
      const long rowg = rowBase + wr * 128 + 16 * i + q * 4 + r;
#pragma unroll
      for (int j = 0; j < 4; ++j) {
        const long colg = colBase + wcn * 64 + 16 * j + l15;
        float v = acc[i][j][r];
        if (BIAS_MODE == 1) v += bias[colg];
        if (BIAS_MODE == 2) v += bias[rowg];
        v *= outScale;
        if (OUT_MODE == 2) ((float*)Cout)[rowg * ldc + colg] = v;
        else               ((_Float16*)Cout)[rowg * ldc + colg] = (_Float16)v;
      }
    }
  }
}

template<int BIAS_MODE, int OUT_MODE, int SWZ>
__global__ __launch_bounds__(512, 2)
void gemmV_k(const _Float16* __restrict__ A, const _Float16* __restrict__ B,
             void* __restrict__ Cout, const float* __restrict__ bias,
             int lda, int ldb, int ldc, int K, float outScale)
{
  __shared__ __align__(16) _Float16 As[3 * 16384];
  __shared__ __align__(16) _Float16 Bs[3 * 8192];

  int tx, ty;
  if (SWZ) {
    const int bflat = blockIdx.y * gridDim.x + blockIdx.x;  // dispatch-linear
    ty = bflat % gridDim.y;
    tx = bflat / gridDim.y;
  } else {
    tx = blockIdx.x; ty = blockIdx.y;
  }
  const long rowBase = (long)ty * 256;
  const long colBase = (long)tx * 128;

  floatx4 acc[4][4] = {};
  kloop_v(A, B, rowBase, colBase, lda, ldb, K, As, Bs, acc);

  const int tid = threadIdx.x;
  const int w = tid >> 6, lane = tid & 63;
  const int q = lane >> 4, l15 = lane & 15;
  const int wr = w >> 1, wcn = w & 1;
#pragma unroll
  for (int i = 0; i < 4; ++i) {
#pragma unroll
    for (int r = 0; r < 4; ++r) {
      const long rowg = rowBase + wr * 64 + 16 * i + q * 4 + r;
#pragma unroll
      for (int j = 0; j < 4; ++j) {
        const long colg = colBase + wcn * 64 + 16 * j + l15;
        float v = acc[i][j][r];
        if (BIAS_MODE == 1) v += bias[colg];
        if (BIAS_MODE == 2) v += bias[rowg];
        if (BIAS_MODE == 3) v *= bias[rowg];
        v *= outScale;
        if (OUT_MODE == 2) ((float*)Cout)[rowg * ldc + colg] = v;
        else               ((_Float16*)Cout)[rowg * ldc + colg] = (_Float16)v;
      }
    }
  }
}

// U = exp(qkScale*(Q*K^T) + decay_bias - 4), fp16; per-(row,col-tile) sums.
// Engine S + fused exp epilogue (v12-validated); sL scratch aliased into As.
__global__ __launch_bounds__(512, 2)
void gemm_statsS_k(const _Float16* __restrict__ A, const _Float16* __restrict__ B,
                   const float* __restrict__ ts, _Float16* __restrict__ U,
                   float* __restrict__ part, int lda, int ldb, int N, int K,
                   float qkScale)
{
  __shared__ __align__(16) _Float16 As[2 * 16384];
  __shared__ __align__(16) _Float16 Bs[2 * 16384];
  const int tid = threadIdx.x;
  const long rowBase = (long)blockIdx.y * 256;
  const long colBase = (long)blockIdx.x * 256;

  floatx4 acc[8][4] = {};
  kloop_s(A, B, rowBase, colBase, lda, ldb, K, As, Bs, acc);

  const int w = tid >> 6, lane = tid & 63;
  const int q = lane >> 4, l15 = lane & 15;
  const int wr = w >> 2, wcn = w & 3;
  const float inv_td = 1.0f / 86400.0f;

  float tc[4];
#pragma unroll
  for (int j = 0; j < 4; ++j) tc[j] = ts[colBase + wcn * 64 + 16 * j + l15];

  float* sl = (float*)As;
  __syncthreads();
  // u = exp(s - 4); s = qk/32 + log-decay ~ qk/32 - |dt|/TD (exact to 2.2e-6).
#pragma unroll
  for (int i = 0; i < 8; ++i) {
#pragma unroll
    for (int r = 0; r < 4; ++r) {
      const int rowl = wr * 128 + 16 * i + q * 4 + r;
      const float tr = ts[rowBase + rowl];
      float ls = 0.0f;
#pragma unroll
      for (int j = 0; j < 4; ++j) {
        const int coll = wcn * 64 + 16 * j + l15;
        const float sv = acc[i][j][r] * qkScale
                       - fabsf(tr - tc[j]) * inv_td - 4.0f;
        const float u = __expf(sv);
        ls += u;
        U[(rowBase + rowl) * (long)N + (colBase + coll)] = (_Float16)u;
      }
      for (int mask = 1; mask <= 8; mask <<= 1)
        ls += __shfl_xor(ls, mask, 64);
      if (l15 == 0) sl[(wr * 4 + wcn) * 128 + 16 * i + 4 * q + r] = ls;
    }
  }
  __syncthreads();
  if (tid < 256) {
    const int band = tid & 127, hi = tid >> 7;
    part[(rowBase + tid) * 32 + blockIdx.x] =
        sl[(hi * 4 + 0) * 128 + band] + sl[(hi * 4 + 1) * 128 + band] +
        sl[(hi * 4 + 2) * 128 + band] + sl[(hi * 4 + 3) * 128 + band];
  }
}

__global__ void combine_k(const float* __restrict__ part, float* __restrict__ invL) {
  const int r = blockIdx.x * 256 + threadIdx.x;
  float L = 0.0f;
  for (int c = 0; c < 32; ++c) L += part[(long)r * 32 + c];
  invL[r] = 1.0f / L;
}

// fp32 -> fp16, 4/thread
__global__ void cvt_k(const float* __restrict__ in, _Float16* __restrict__ out, int n) {
  const int i = (blockIdx.x * 256 + threadIdx.x) * 4;
  if (i >= n) return;
  const float4 v = *(const float4*)(in + i);
  half4 o = { (_Float16)v.x, (_Float16)v.y, (_Float16)v.z, (_Float16)v.w };
  *(half4*)(out + i) = o;
}

extern "C" void kernel_launch(void* const* d_in, const int* in_sizes, int n_in,
                              void* d_out, int out_size, void* d_ws, size_t ws_size,
                              hipStream_t stream)
{
  (void)in_sizes; (void)n_in; (void)out_size; (void)ws_size;
  const int N = 8192, D = 1024;
  const float* x  = (const float*)d_in[0];
  const float* ts = (const float*)d_in[1];
  const float* Wq = (const float*)d_in[2];
  const float* bq = (const float*)d_in[3];
  const float* Wk = (const float*)d_in[4];
  const float* bk = (const float*)d_in[5];
  const float* Wv = (const float*)d_in[6];
  const float* bv = (const float*)d_in[7];

  char* p = (char*)d_ws;
  auto grab = [&](size_t bytes) {
    char* r = p;
    p += (bytes + 255) & ~(size_t)255;
    return r;
  };
  _Float16* xh    = (_Float16*)grab((size_t)N * D * 2);
  _Float16* wqkh  = (_Float16*)grab((size_t)2 * D * D * 2); // Wq rows then Wk rows
  _Float16* wvh   = (_Float16*)grab((size_t)D * D * 2);
  _Float16* QKcat = (_Float16*)grab((size_t)N * 2 * D * 2); // [N x 2D], Q | K
  _Float16* VTh   = (_Float16*)grab((size_t)D * N * 2);     // V^T [D x N]
  _Float16* Uh    = (_Float16*)grab((size_t)N * N * 2);     // U = exp(S - 4)
  float*    part  = (float*)grab((size_t)N * 32 * sizeof(float));
  float*    invL  = (float*)grab((size_t)N * sizeof(float));
  float*    bcat  = (float*)grab((size_t)2 * D * sizeof(float));

  cvt_k<<<N * D / 1024, 256, 0, stream>>>(x,  xh,  N * D);
  cvt_k<<<D * D / 1024, 256, 0, stream>>>(Wq, wqkh,         D * D);
  cvt_k<<<D * D / 1024, 256, 0, stream>>>(Wk, wqkh + D * D, D * D);
  cvt_k<<<D * D / 1024, 256, 0, stream>>>(Wv, wvh, D * D);
  hipMemcpyAsync(bcat,     bq, D * sizeof(float), hipMemcpyDeviceToDevice, stream);
  hipMemcpyAsync(bcat + D, bk, D * sizeof(float), hipMemcpyDeviceToDevice, stream);

  dim3 blk(512);
  // [Q | K] = x [Wq;Wk]^T + [bq|bk]; engine S -> grid (8,32)=256 wg.
  gemmS_k<1, 0><<<dim3(2 * D / 256, N / 256), blk, 0, stream>>>(
      xh, wqkh, QKcat, bcat, D, D, 2 * D, D, 1.0f);
  // V^T = Wv x^T + bv; engine V -> grid (64,4)=256 wg.
  gemmV_k<2, 0, 0><<<dim3(N / 128, D / 256), blk, 0, stream>>>(
      wvh, xh, VTh, bv, D, D, N, D, 1.0f);
  // U = exp(QK^T/32 + decay - 4) + partial row sums; engine S, (32,32)=1024 wg.
  gemm_statsS_k<<<dim3(N / 256, N / 256), blk, 0, stream>>>(
      QKcat, QKcat + D, ts, Uh, part, 2 * D, 2 * D, N, D, 1.0f / 32.0f);
  combine_k<<<N / 256, 256, 0, stream>>>(part, invL);
  // O = (U V) * invL; engine V -> grid (8,32)=256 wg, XCD swz.
  gemmV_k<3, 2, 1><<<dim3(D / 128, N / 256), blk, 0, stream>>>(
      Uh, VTh, d_out, invL, N, N, D, N, 1.0f);
}